// Round 12
// baseline (63.890 us; speedup 1.0000x reference)
//
#include <hip/hip_runtime.h>
#include <hip/hip_bf16.h>

#define B_ 8
#define T_ 2048
#define C_ 1024
#define HS_ 64

typedef float f32x4 __attribute__((ext_vector_type(4)));
typedef __bf16 bf16x8 __attribute__((ext_vector_type(8)));
typedef __bf16 bf16x4 __attribute__((ext_vector_type(4)));

__device__ __forceinline__ void gld_lds16(const void* g, void* l) {
    __builtin_amdgcn_global_load_lds(
        (const __attribute__((address_space(1))) void*)g,
        (__attribute__((address_space(3))) void*)l, 16, 0, 0);
}

// Workspaces:
//  wt[192][1024] bf16, PRE-SWIZZLED per 64-col k-tile: chunk c (16B) of row
//  rw holds original chunk c^(rw&7) (rule #21: source perm == read perm).
//  Rows 0-63 Wq^T (scaled 1/32 * log2(e) -> scores in log2 domain),
//  64-127 Wk^T, 128-191 Wv^T.
//  Qf[b*128+qt16][2 half][64 lane][8] : word = Q[qt*16+(lane&15)][half*32+(lane>>4)*8+j]
//  Kf identical mapping. Vf[b*64+kt32][4 ntv][64][8]:
//  word = V[kt32*32+(lane>>4)*8+j][ntv*16+(lane&15)]
//  NOTE: a 64-key K tile = 4 consecutive kt16 groups = 8KB contiguous in Kf;
//  a 64-key V tile = 2 consecutive kt32 groups = 8KB contiguous in Vf ->
//  global_load_lds staging is LINEAR (no swizzle needed).

// ---------------------------------------------------------------------------
// Kernel 1: W [1024][64] fp32 -> wt [192][1024] bf16 (r11-exact).
// ---------------------------------------------------------------------------
__global__ __launch_bounds__(256) void wt_kernel(const float* __restrict__ Wq,
                                                 const float* __restrict__ Wk,
                                                 const float* __restrict__ Wv,
                                                 __bf16* __restrict__ wt) {
    __shared__ float tile[64][65];
    int mb = blockIdx.x >> 4;
    int k0 = (blockIdx.x & 15) * 64;
    const float* W = (mb == 0) ? Wq : (mb == 1 ? Wk : Wv);
    int c = threadIdx.x & 63;
#pragma unroll
    for (int r = threadIdx.x >> 6; r < 64; r += 4)
        tile[r][c] = W[(size_t)(k0 + r) * 64 + c];
    __syncthreads();
    float scale = (mb == 0) ? (0.03125f * 1.44269504f) : 1.0f;
    int kk = threadIdx.x & 63;
#pragma unroll
    for (int n = threadIdx.x >> 6; n < 64; n += 4) {
        int col = (((kk >> 3) ^ (n & 7)) * 8) + (kk & 7);
        wt[(size_t)(mb * 64 + n) * C_ + k0 + col] = (__bf16)(tile[kk][n] * scale);
    }
}

// ---------------------------------------------------------------------------
// Kernel 2: QKV GEMM (r11-exact). 512 blocks x 512 thr. 32 rows x 192 cols,
// K-step 64, W via global_load_lds from pre-swizzled wt, x reg-staged.
// ---------------------------------------------------------------------------
__global__ __launch_bounds__(512) void qkv_kernel(const float* __restrict__ x,
                                                  const __bf16* __restrict__ wt,
                                                  __bf16* __restrict__ qf,
                                                  __bf16* __restrict__ kf,
                                                  __bf16* __restrict__ vf) {
    __shared__ __align__(16) char smem[57344];
    __bf16* xs0 = (__bf16*)smem;               // [32][64] swz, 4KB
    __bf16* xs1 = (__bf16*)(smem + 4096);
    __bf16* ws0 = (__bf16*)(smem + 8192);      // [192][64] swz, 24KB
    __bf16* ws1 = (__bf16*)(smem + 32768);

    const int tid = threadIdx.x;
    const int w = tid >> 6, lane = tid & 63, lq = lane & 15, lg = lane >> 4;
    const int m0 = blockIdx.x * 32;
    const int mt = w & 1;
    const int ntb = (w >> 1) * 3;

    f32x4 acc[3];
#pragma unroll
    for (int i = 0; i < 3; ++i) acc[i] = (f32x4)0.0f;

    const int xrow = tid >> 3, xch = tid & 7;
    float4 xr0, xr1;
    const int wslot0 = w * 3 * 64 + lane;

    if (tid < 256) {
        const float* xp = x + (size_t)(m0 + xrow) * C_ + xch * 8;
        xr0 = *(const float4*)xp;
        xr1 = *(const float4*)(xp + 4);
    }
#pragma unroll
    for (int s = 0; s < 3; ++s) {
        int slot = wslot0 + s * 64;
        gld_lds16(wt + (size_t)(slot >> 3) * C_ + (slot & 7) * 8,
                  ws0 + (w * 3 + s) * 512);
    }
    if (tid < 256) {
        bf16x8 xb;
#pragma unroll
        for (int j = 0; j < 4; ++j) { xb[j] = (__bf16)xr0[j]; xb[4 + j] = (__bf16)xr1[j]; }
        *(bf16x8*)(xs0 + xrow * 64 + ((xch ^ (xrow & 7)) * 8)) = xb;
    }

    for (int kt = 0; kt < 16; ++kt) {
        __syncthreads();
        __bf16* xsc = (kt & 1) ? xs1 : xs0;
        __bf16* wsc = (kt & 1) ? ws1 : ws0;
        __bf16* xsn = (kt & 1) ? xs0 : xs1;
        __bf16* wsn = (kt & 1) ? ws0 : ws1;
        if (kt < 15) {
            int k0 = (kt + 1) * 64;
            if (tid < 256) {
                const float* xp = x + (size_t)(m0 + xrow) * C_ + k0 + xch * 8;
                xr0 = *(const float4*)xp;
                xr1 = *(const float4*)(xp + 4);
            }
#pragma unroll
            for (int s = 0; s < 3; ++s) {
                int slot = wslot0 + s * 64;
                gld_lds16(wt + (size_t)(slot >> 3) * C_ + k0 + (slot & 7) * 8,
                          wsn + (w * 3 + s) * 512);
            }
        }
#pragma unroll
        for (int ks = 0; ks < 2; ++ks) {
            int r = mt * 16 + lq;
            bf16x8 a = *(const bf16x8*)(xsc + r * 64 + (((ks * 4 + lg) ^ (r & 7)) * 8));
#pragma unroll
            for (int i = 0; i < 3; ++i) {
                int rw = (ntb + i) * 16 + lq;
                bf16x8 b = *(const bf16x8*)(wsc + rw * 64 + (((ks * 4 + lg) ^ (rw & 7)) * 8));
                acc[i] = __builtin_amdgcn_mfma_f32_16x16x32_bf16(a, b, acc[i], 0, 0, 0);
            }
        }
        if (kt < 15 && tid < 256) {
            bf16x8 xb;
#pragma unroll
            for (int j = 0; j < 4; ++j) { xb[j] = (__bf16)xr0[j]; xb[4 + j] = (__bf16)xr1[j]; }
            *(bf16x8*)(xsn + xrow * 64 + ((xch ^ (xrow & 7)) * 8)) = xb;
        }
    }
    __syncthreads();

    __bf16(*obuf)[208] = (__bf16(*)[208])smem;
#pragma unroll
    for (int i = 0; i < 3; ++i)
#pragma unroll
        for (int r = 0; r < 4; ++r)
            obuf[mt * 16 + lg * 4 + r][(ntb + i) * 16 + lq] = (__bf16)acc[i][r];
    __syncthreads();

    if (w < 4) {
        int mg = w & 1, half = w >> 1;
        size_t qt16 = (size_t)(m0 >> 4) + mg;
        bf16x8 vq = *(const bf16x8*)&obuf[mg * 16 + lq][half * 32 + lg * 8];
        bf16x8 vk = *(const bf16x8*)&obuf[mg * 16 + lq][64 + half * 32 + lg * 8];
        *(bf16x8*)(qf + ((qt16 * 2 + half) * 64 + lane) * 8) = vq;
        *(bf16x8*)(kf + ((qt16 * 2 + half) * 64 + lane) * 8) = vk;
    } else {
        int ntv = w - 4;
        bf16x8 vv;
#pragma unroll
        for (int j = 0; j < 8; ++j)
            vv[j] = obuf[lg * 8 + j][128 + ntv * 16 + lq];
        size_t kt32 = (size_t)(m0 >> 5);
        *(bf16x8*)(vf + ((kt32 * 4 + ntv) * 64 + lane) * 8) = vv;
    }
}

// ---------------------------------------------------------------------------
// Kernel 3: causal flash attention, BLOCK-COOPERATIVE K/V STAGING.
// 256 blocks x 4 waves. Block owns Q64 (wave w: queries q0+w*16..+15); all
// waves walk the same kt sequence; each 64-key K+V tile (16KB, contiguous
// in fragment layout) staged once per block via global_load_lds, double-
// buffered. No cross-wave combine: each wave owns all keys for its queries,
// direct register writeout. Softmax in exp2 domain.
// ---------------------------------------------------------------------------
__global__ __launch_bounds__(256) void attn_kernel(const __bf16* __restrict__ qf,
                                                   const __bf16* __restrict__ kf,
                                                   const __bf16* __restrict__ vf,
                                                   float* __restrict__ out) {
    // buf0 @0 (16KB: K 8KB | V 8KB), buf1 @16384, plds @32768 (4 x 2304B)
    __shared__ __align__(16) char smem[41984];

    const int tid = threadIdx.x;
    const int w = tid >> 6, lane = tid & 63, lq = lane & 15, lg = lane >> 4;
    const int b  = blockIdx.x & 7;             // batch -> XCD affinity
    const int q0 = (31 - (blockIdx.x >> 3)) * 64;   // heavy blocks first
    const int qt = q0 + w * 16;

    // Q A-fragments
    size_t qbase = ((size_t)b * 128 + (qt >> 4)) * 2;
    bf16x8 aq0 = *(const bf16x8*)(qf + ((qbase + 0) * 64 + lane) * 8);
    bf16x8 aq1 = *(const bf16x8*)(qf + ((qbase + 1) * 64 + lane) * 8);

    f32x4 o[4];
#pragma unroll
    for (int nt = 0; nt < 4; ++nt) o[nt] = (f32x4)0.0f;
    float m_s = -1e30f, l_s = 0.f;

    __bf16* pw = (__bf16*)(smem + 32768 + w * 2304);

    const int ntiles = (q0 >> 6) + 1;

    // stage tile t into dst: K tile 8KB then V tile 8KB, linear chunks.
    // thread's 4 chunks: K {tid, tid+256}, V {tid, tid+256}.
#define STAGE(T, DST)                                                          \
    {                                                                          \
        int s0_ = (T) * 64;                                                    \
        const __bf16* ks_ = kf + ((size_t)b * 128 + (s0_ >> 4)) * 1024;        \
        const __bf16* vs_ = vf + ((size_t)b * 64 + (s0_ >> 5)) * 2048;         \
        gld_lds16(ks_ + (size_t)tid * 8,         (DST) + tid * 16);            \
        gld_lds16(ks_ + (size_t)(tid + 256) * 8, (DST) + (tid + 256) * 16);    \
        gld_lds16(vs_ + (size_t)tid * 8,         (DST) + 8192 + tid * 16);     \
        gld_lds16(vs_ + (size_t)(tid + 256) * 8, (DST) + 8192 + (tid + 256) * 16); \
    }

    STAGE(0, smem);

    for (int kt = 0; kt < ntiles; ++kt) {
        __syncthreads();   // staging of buf[kt&1] complete; reads of buf[1-kt&1] done
        char* cbuf = smem + (kt & 1) * 16384;
        if (kt + 1 < ntiles) {
            char* nbuf = smem + ((kt + 1) & 1) * 16384;
            STAGE(kt + 1, nbuf);
        }
        const __bf16* kb = (const __bf16*)cbuf;
        const __bf16* vb = (const __bf16*)(cbuf + 8192);
        int s0 = kt * 64;

        // S^T = K Q^T from LDS fragments
        f32x4 s[4];
        __builtin_amdgcn_s_setprio(1);
#pragma unroll
        for (int ct = 0; ct < 4; ++ct) {
            bf16x8 k0 = *(const bf16x8*)(kb + (ct * 2 + 0) * 512 + lane * 8);
            bf16x8 k1 = *(const bf16x8*)(kb + (ct * 2 + 1) * 512 + lane * 8);
            f32x4 a = (f32x4)0.0f;
            a = __builtin_amdgcn_mfma_f32_16x16x32_bf16(k0, aq0, a, 0, 0, 0);
            a = __builtin_amdgcn_mfma_f32_16x16x32_bf16(k1, aq1, a, 0, 0, 0);
            s[ct] = a;
        }
        __builtin_amdgcn_s_setprio(0);
        // causal mask: key = s0+ct*16+lg*4+r vs query = qt+lq
        if (s0 + 63 > qt) {
#pragma unroll
            for (int ct = 0; ct < 4; ++ct)
#pragma unroll
                for (int r = 0; r < 4; ++r)
                    if (s0 + ct * 16 + lg * 4 + r > qt + lq) s[ct][r] = -1e30f;
        }
        // online softmax (exp2 domain), defer-max (exact)
        float pm = -1e30f;
#pragma unroll
        for (int ct = 0; ct < 4; ++ct)
#pragma unroll
            for (int r = 0; r < 4; ++r) pm = fmaxf(pm, s[ct][r]);
        pm = fmaxf(pm, __shfl_xor(pm, 16));
        pm = fmaxf(pm, __shfl_xor(pm, 32));
        bool need = __any(pm > m_s);
        float al = 1.0f;
        if (need) {
            float mn = fmaxf(m_s, pm);
            al = exp2f(m_s - mn);
            m_s = mn;
        }
        float rs = 0.f;
        f32x4 p[4];
#pragma unroll
        for (int ct = 0; ct < 4; ++ct)
#pragma unroll
            for (int r = 0; r < 4; ++r) {
                p[ct][r] = exp2f(s[ct][r] - m_s);
                rs += p[ct][r];
            }
        rs += __shfl_xor(rs, 16);
        rs += __shfl_xor(rs, 32);
        if (need) {
            l_s = l_s * al + rs;
            float alr[4];
#pragma unroll
            for (int r = 0; r < 4; ++r) alr[r] = __shfl(al, lg * 4 + r);
#pragma unroll
            for (int nt = 0; nt < 4; ++nt)
#pragma unroll
                for (int r = 0; r < 4; ++r) o[nt][r] *= alr[r];
        } else {
            l_s += rs;
        }
        // P -> LDS (row = query lq, cols = 64 keys)
#pragma unroll
        for (int ct = 0; ct < 4; ++ct) {
            bf16x4 qv;
#pragma unroll
            for (int r = 0; r < 4; ++r) qv[r] = (__bf16)p[ct][r];
            *(bf16x4*)&pw[lq * 72 + ct * 16 + lg * 4] = qv;
        }
        asm volatile("" ::: "memory");
        bf16x8 pa0 = *(const bf16x8*)&pw[lq * 72 + lg * 8];
        bf16x8 pa1 = *(const bf16x8*)&pw[lq * 72 + 32 + lg * 8];
        __builtin_amdgcn_s_setprio(1);
#pragma unroll
        for (int nt = 0; nt < 4; ++nt) {
            bf16x8 bv0 = *(const bf16x8*)(vb + (0 * 4 + nt) * 512 + lane * 8);
            o[nt] = __builtin_amdgcn_mfma_f32_16x16x32_bf16(pa0, bv0, o[nt], 0, 0, 0);
            bf16x8 bv1 = *(const bf16x8*)(vb + (1 * 4 + nt) * 512 + lane * 8);
            o[nt] = __builtin_amdgcn_mfma_f32_16x16x32_bf16(pa1, bv1, o[nt], 0, 0, 0);
        }
        __builtin_amdgcn_s_setprio(0);
    }
#undef STAGE

    // direct writeout: row = qt + lg*4 + r, col = nt*16 + lq; l for row
    // lg*4+r lives in lane lg*4+r (its lq == row index)
    float rcp = 1.0f / l_s;
    float inv[4];
#pragma unroll
    for (int r = 0; r < 4; ++r) inv[r] = __shfl(rcp, lg * 4 + r);
    float* ob = out + ((size_t)b * T_ + qt) * HS_;
#pragma unroll
    for (int nt = 0; nt < 4; ++nt)
#pragma unroll
        for (int r = 0; r < 4; ++r)
            ob[(size_t)(lg * 4 + r) * HS_ + nt * 16 + lq] = o[nt][r] * inv[r];
}

extern "C" void kernel_launch(void* const* d_in, const int* in_sizes, int n_in,
                              void* d_out, int out_size, void* d_ws, size_t ws_size,
                              hipStream_t stream) {
    const float* x  = (const float*)d_in[0];
    const float* Wq = (const float*)d_in[1];
    const float* Wk = (const float*)d_in[2];
    const float* Wv = (const float*)d_in[3];
    char* ws = (char*)d_ws;
    __bf16* wt = (__bf16*)ws;                     // 393216 B
    __bf16* qf = (__bf16*)(ws + 393216);          // 2 MB
    __bf16* kf = (__bf16*)(ws + 2490368);         // 2 MB
    __bf16* vf = (__bf16*)(ws + 4587520);         // 2 MB
    float* out = (float*)d_out;

    wt_kernel<<<dim3(48), dim3(256), 0, stream>>>(Wq, Wk, Wv, wt);
    qkv_kernel<<<dim3(512), dim3(512), 0, stream>>>(x, wt, qf, kf, vf);
    attn_kernel<<<dim3(256), dim3(256), 0, stream>>>(qf, kf, vf, out);
}

// Round 13
// 53.837 us; speedup vs baseline: 1.1867x; 1.1867x over previous
//
#include <hip/hip_runtime.h>
#include <hip/hip_bf16.h>

#define B_ 8
#define T_ 2048
#define C_ 1024
#define HS_ 64

typedef float f32x4 __attribute__((ext_vector_type(4)));
typedef __bf16 bf16x8 __attribute__((ext_vector_type(8)));
typedef __bf16 bf16x4 __attribute__((ext_vector_type(4)));

__device__ __forceinline__ void gld_lds16(const void* g, void* l) {
    __builtin_amdgcn_global_load_lds(
        (const __attribute__((address_space(1))) void*)g,
        (__attribute__((address_space(3))) void*)l, 16, 0, 0);
}

// Workspaces:
//  wt[192][1024] bf16, PRE-SWIZZLED per 64-col k-tile: chunk c (16B) of row
//  rw holds original chunk c^(rw&7) (rule #21: source perm == read perm).
//  Rows 0-63 Wq^T (scaled 1/32), 64-127 Wk^T, 128-191 Wv^T.
//  Qf[b*128+qt16][2 half][64 lane][8] : word = Q[qt*16+(lane&15)][half*32+(lane>>4)*8+j]
//  Kf identical mapping. Vf[b*64+kt32][4 ntv][64][8]:
//  word = V[kt32*32+(lane>>4)*8+j][ntv*16+(lane&15)]

// ---------------------------------------------------------------------------
// Kernel 1: W [1024][64] fp32 -> wt [192][1024] bf16 (r9-exact).
// ---------------------------------------------------------------------------
__global__ __launch_bounds__(256) void wt_kernel(const float* __restrict__ Wq,
                                                 const float* __restrict__ Wk,
                                                 const float* __restrict__ Wv,
                                                 __bf16* __restrict__ wt) {
    __shared__ float tile[64][65];
    int mb = blockIdx.x >> 4;
    int k0 = (blockIdx.x & 15) * 64;
    const float* W = (mb == 0) ? Wq : (mb == 1 ? Wk : Wv);
    int c = threadIdx.x & 63;
#pragma unroll
    for (int r = threadIdx.x >> 6; r < 64; r += 4)
        tile[r][c] = W[(size_t)(k0 + r) * 64 + c];
    __syncthreads();
    float scale = (mb == 0) ? 0.03125f : 1.0f;
    int kk = threadIdx.x & 63;
#pragma unroll
    for (int n = threadIdx.x >> 6; n < 64; n += 4) {
        int col = (((kk >> 3) ^ (n & 7)) * 8) + (kk & 7);
        wt[(size_t)(mb * 64 + n) * C_ + k0 + col] = (__bf16)(tile[kk][n] * scale);
    }
}

// ---------------------------------------------------------------------------
// Kernel 2: QKV GEMM (r9-exact). 512 blocks x 512 thr. 32 rows x 192 cols,
// K-step 64, W via global_load_lds from pre-swizzled wt, x reg-staged.
// ---------------------------------------------------------------------------
__global__ __launch_bounds__(512) void qkv_kernel(const float* __restrict__ x,
                                                  const __bf16* __restrict__ wt,
                                                  __bf16* __restrict__ qf,
                                                  __bf16* __restrict__ kf,
                                                  __bf16* __restrict__ vf) {
    __shared__ __align__(16) char smem[57344];
    __bf16* xs0 = (__bf16*)smem;               // [32][64] swz, 4KB
    __bf16* xs1 = (__bf16*)(smem + 4096);
    __bf16* ws0 = (__bf16*)(smem + 8192);      // [192][64] swz, 24KB
    __bf16* ws1 = (__bf16*)(smem + 32768);

    const int tid = threadIdx.x;
    const int w = tid >> 6, lane = tid & 63, lq = lane & 15, lg = lane >> 4;
    const int m0 = blockIdx.x * 32;
    const int mt = w & 1;
    const int ntb = (w >> 1) * 3;

    f32x4 acc[3];
#pragma unroll
    for (int i = 0; i < 3; ++i) acc[i] = (f32x4)0.0f;

    const int xrow = tid >> 3, xch = tid & 7;
    float4 xr0, xr1;
    const int wslot0 = w * 3 * 64 + lane;

    if (tid < 256) {
        const float* xp = x + (size_t)(m0 + xrow) * C_ + xch * 8;
        xr0 = *(const float4*)xp;
        xr1 = *(const float4*)(xp + 4);
    }
#pragma unroll
    for (int s = 0; s < 3; ++s) {
        int slot = wslot0 + s * 64;
        gld_lds16(wt + (size_t)(slot >> 3) * C_ + (slot & 7) * 8,
                  ws0 + (w * 3 + s) * 512);
    }
    if (tid < 256) {
        bf16x8 xb;
#pragma unroll
        for (int j = 0; j < 4; ++j) { xb[j] = (__bf16)xr0[j]; xb[4 + j] = (__bf16)xr1[j]; }
        *(bf16x8*)(xs0 + xrow * 64 + ((xch ^ (xrow & 7)) * 8)) = xb;
    }

    for (int kt = 0; kt < 16; ++kt) {
        __syncthreads();
        __bf16* xsc = (kt & 1) ? xs1 : xs0;
        __bf16* wsc = (kt & 1) ? ws1 : ws0;
        __bf16* xsn = (kt & 1) ? xs0 : xs1;
        __bf16* wsn = (kt & 1) ? ws0 : ws1;
        if (kt < 15) {
            int k0 = (kt + 1) * 64;
            if (tid < 256) {
                const float* xp = x + (size_t)(m0 + xrow) * C_ + k0 + xch * 8;
                xr0 = *(const float4*)xp;
                xr1 = *(const float4*)(xp + 4);
            }
#pragma unroll
            for (int s = 0; s < 3; ++s) {
                int slot = wslot0 + s * 64;
                gld_lds16(wt + (size_t)(slot >> 3) * C_ + k0 + (slot & 7) * 8,
                          wsn + (w * 3 + s) * 512);
            }
        }
#pragma unroll
        for (int ks = 0; ks < 2; ++ks) {
            int r = mt * 16 + lq;
            bf16x8 a = *(const bf16x8*)(xsc + r * 64 + (((ks * 4 + lg) ^ (r & 7)) * 8));
#pragma unroll
            for (int i = 0; i < 3; ++i) {
                int rw = (ntb + i) * 16 + lq;
                bf16x8 b = *(const bf16x8*)(wsc + rw * 64 + (((ks * 4 + lg) ^ (rw & 7)) * 8));
                acc[i] = __builtin_amdgcn_mfma_f32_16x16x32_bf16(a, b, acc[i], 0, 0, 0);
            }
        }
        if (kt < 15 && tid < 256) {
            bf16x8 xb;
#pragma unroll
            for (int j = 0; j < 4; ++j) { xb[j] = (__bf16)xr0[j]; xb[4 + j] = (__bf16)xr1[j]; }
            *(bf16x8*)(xsn + xrow * 64 + ((xch ^ (xrow & 7)) * 8)) = xb;
        }
    }
    __syncthreads();

    __bf16(*obuf)[208] = (__bf16(*)[208])smem;
#pragma unroll
    for (int i = 0; i < 3; ++i)
#pragma unroll
        for (int r = 0; r < 4; ++r)
            obuf[mt * 16 + lg * 4 + r][(ntb + i) * 16 + lq] = (__bf16)acc[i][r];
    __syncthreads();

    if (w < 4) {
        int mg = w & 1, half = w >> 1;
        size_t qt16 = (size_t)(m0 >> 4) + mg;
        bf16x8 vq = *(const bf16x8*)&obuf[mg * 16 + lq][half * 32 + lg * 8];
        bf16x8 vk = *(const bf16x8*)&obuf[mg * 16 + lq][64 + half * 32 + lg * 8];
        *(bf16x8*)(qf + ((qt16 * 2 + half) * 64 + lane) * 8) = vq;
        *(bf16x8*)(kf + ((qt16 * 2 + half) * 64 + lane) * 8) = vk;
    } else {
        int ntv = w - 4;
        bf16x8 vv;
#pragma unroll
        for (int j = 0; j < 8; ++j)
            vv[j] = obuf[lg * 8 + j][128 + ntv * 16 + lq];
        size_t kt32 = (size_t)(m0 >> 5);
        *(bf16x8*)(vf + ((kt32 * 4 + ntv) * 64 + lane) * 8) = vv;
    }
}

// ---------------------------------------------------------------------------
// Kernel 3: causal flash attention — r9 structure, occupancy-tuned:
// KVBLK=32 (s[2], bv[4]: small reg state), exp in place (no p[]),
// plds/olds LDS UNION (33.8KB -> 4 blocks/CU), launch_bounds(512,8)
// forcing VGPR<=64 -> 8 waves/SIMD. 512 blocks x 8 waves; wave-paired Q32;
// swapped QK^T; defer-max; V-prefetch; flash-combine per 4-wave half.
// ---------------------------------------------------------------------------
__global__ __launch_bounds__(512, 8) void attn_kernel(const __bf16* __restrict__ qf,
                                                      const __bf16* __restrict__ kf,
                                                      const __bf16* __restrict__ vf,
                                                      float* __restrict__ out) {
    // union: plds [8][16*40] bf16 (10240B, loop) / olds [8][16][64] f32
    // (32768B, post-loop; barrier separates). + mlds/llds 1KB.
    __shared__ __align__(16) char smem[33792];
    float* mlds = (float*)(smem + 32768);        // [8][16]
    float* llds = (float*)(smem + 33280);        // [8][16]

    const int tid = threadIdx.x;
    const int w = tid >> 6, lane = tid & 63, lq = lane & 15, lg = lane >> 4;

    const int b  = blockIdx.x & 7;                 // batch -> XCD affinity
    const int q0 = (63 - (blockIdx.x >> 3)) * 32;  // heavy tiles first
    const int qs = w >> 2;                         // query sub-tile
    const int wk = w & 3;                          // kt round-robin slot
    const int qt = q0 + qs * 16;

    size_t qbase = ((size_t)b * 128 + (qt >> 4)) * 2;
    bf16x8 aq0 = *(const bf16x8*)(qf + ((qbase + 0) * 64 + lane) * 8);
    bf16x8 aq1 = *(const bf16x8*)(qf + ((qbase + 1) * 64 + lane) * 8);

    f32x4 o[4];
#pragma unroll
    for (int nt = 0; nt < 4; ++nt) o[nt] = (f32x4)0.0f;
    float m_s = -1e30f, l_s = 0.f;

    __bf16* pw = (__bf16*)(smem + w * 1280);   // [16][40] per wave

    int ntiles = (qt + 47) >> 5;   // ceil((qt+16)/32), 32-key tiles
    for (int kt = wk; kt < ntiles; kt += 4) {
        int s0 = kt * 32;
        // S^T = K Q^T : col = query (lq), row = key
        f32x4 s[2];
        __builtin_amdgcn_s_setprio(1);
#pragma unroll
        for (int ct = 0; ct < 2; ++ct) {
            size_t kbase = ((size_t)b * 128 + (s0 >> 4) + ct) * 2;
            bf16x8 k0 = *(const bf16x8*)(kf + ((kbase + 0) * 64 + lane) * 8);
            bf16x8 k1 = *(const bf16x8*)(kf + ((kbase + 1) * 64 + lane) * 8);
            f32x4 a = (f32x4)0.0f;
            a = __builtin_amdgcn_mfma_f32_16x16x32_bf16(k0, aq0, a, 0, 0, 0);
            a = __builtin_amdgcn_mfma_f32_16x16x32_bf16(k1, aq1, a, 0, 0, 0);
            s[ct] = a;
        }
        __builtin_amdgcn_s_setprio(0);
        // causal mask: key = s0+ct*16+lg*4+r vs query = qt+lq
        if (s0 + 31 > qt) {
#pragma unroll
            for (int ct = 0; ct < 2; ++ct)
#pragma unroll
                for (int r = 0; r < 4; ++r)
                    if (s0 + ct * 16 + lg * 4 + r > qt + lq) s[ct][r] = -1e30f;
        }
        // V prefetch (4 frags, independent of softmax)
        bf16x8 bv[4];
#pragma unroll
        for (int nt = 0; nt < 4; ++nt)
            bv[nt] = *(const bf16x8*)(vf +
                (((size_t)(b * 64 + (s0 >> 5)) * 4 + nt) * 64 + lane) * 8);
        // online softmax, defer-max (exact), exp in place
        float pm = fmaxf(fmaxf(fmaxf(s[0][0], s[0][1]), fmaxf(s[0][2], s[0][3])),
                         fmaxf(fmaxf(s[1][0], s[1][1]), fmaxf(s[1][2], s[1][3])));
        pm = fmaxf(pm, __shfl_xor(pm, 16));
        pm = fmaxf(pm, __shfl_xor(pm, 32));
        bool need = __any(pm > m_s);
        float al = 1.0f;
        if (need) {
            float mn = fmaxf(m_s, pm);
            al = __expf(m_s - mn);
            m_s = mn;
        }
        float rs = 0.f;
#pragma unroll
        for (int ct = 0; ct < 2; ++ct)
#pragma unroll
            for (int r = 0; r < 4; ++r) {
                s[ct][r] = __expf(s[ct][r] - m_s);
                rs += s[ct][r];
            }
        rs += __shfl_xor(rs, 16);
        rs += __shfl_xor(rs, 32);
        if (need) {
            l_s = l_s * al + rs;
            float alr[4];
#pragma unroll
            for (int r = 0; r < 4; ++r) alr[r] = __shfl(al, lg * 4 + r);
#pragma unroll
            for (int nt = 0; nt < 4; ++nt)
#pragma unroll
                for (int r = 0; r < 4; ++r) o[nt][r] *= alr[r];
        } else {
            l_s += rs;
        }
        // P -> LDS: row = query lq (stride 40), cols = 32 keys
#pragma unroll
        for (int ct = 0; ct < 2; ++ct) {
            bf16x4 qv;
#pragma unroll
            for (int r = 0; r < 4; ++r) qv[r] = (__bf16)s[ct][r];
            *(bf16x4*)&pw[lq * 40 + ct * 16 + lg * 4] = qv;
        }
        asm volatile("" ::: "memory");
        bf16x8 pa = *(const bf16x8*)&pw[lq * 40 + lg * 8];
        __builtin_amdgcn_s_setprio(1);
#pragma unroll
        for (int nt = 0; nt < 4; ++nt)
            o[nt] = __builtin_amdgcn_mfma_f32_16x16x32_bf16(pa, bv[nt], o[nt], 0, 0, 0);
        __builtin_amdgcn_s_setprio(0);
    }

    // all waves done with plds before olds overlays it
    __syncthreads();
    float* olds = (float*)smem;                 // [8][16][64]
#pragma unroll
    for (int nt = 0; nt < 4; ++nt)
#pragma unroll
        for (int r = 0; r < 4; ++r)
            olds[(w * 16 + lg * 4 + r) * 64 + nt * 16 + lq] = o[nt][r];
    if (lg == 0) {
        mlds[w * 16 + lq] = m_s;
        llds[w * 16 + lq] = l_s;
    }
    __syncthreads();

    // flash-combine: 32 rows x 16 col-quads; each half-row combines its 4 waves
    int row = tid >> 4;
    int c4  = (tid & 15) * 4;
    int wb  = (row >> 4) * 4;
    int r16 = row & 15;
    float M = -1e30f;
#pragma unroll
    for (int w2 = 0; w2 < 4; ++w2) M = fmaxf(M, mlds[(wb + w2) * 16 + r16]);
    float L = 0.f;
    f32x4 oa = (f32x4)0.0f;
#pragma unroll
    for (int w2 = 0; w2 < 4; ++w2) {
        float sc = __expf(mlds[(wb + w2) * 16 + r16] - M);
        L += sc * llds[(wb + w2) * 16 + r16];
        const float* op = olds + ((wb + w2) * 16 + r16) * 64 + c4;
#pragma unroll
        for (int j = 0; j < 4; ++j) oa[j] += sc * op[j];
    }
    float inv = 1.0f / L;
    float4 st;
    st.x = oa[0] * inv; st.y = oa[1] * inv; st.z = oa[2] * inv; st.w = oa[3] * inv;
    *(float4*)(out + ((size_t)b * T_ + q0 + row) * HS_ + c4) = st;
}

extern "C" void kernel_launch(void* const* d_in, const int* in_sizes, int n_in,
                              void* d_out, int out_size, void* d_ws, size_t ws_size,
                              hipStream_t stream) {
    const float* x  = (const float*)d_in[0];
    const float* Wq = (const float*)d_in[1];
    const float* Wk = (const float*)d_in[2];
    const float* Wv = (const float*)d_in[3];
    char* ws = (char*)d_ws;
    __bf16* wt = (__bf16*)ws;                     // 393216 B
    __bf16* qf = (__bf16*)(ws + 393216);          // 2 MB
    __bf16* kf = (__bf16*)(ws + 2490368);         // 2 MB
    __bf16* vf = (__bf16*)(ws + 4587520);         // 2 MB
    float* out = (float*)d_out;

    wt_kernel<<<dim3(48), dim3(256), 0, stream>>>(Wq, Wk, Wv, wt);
    qkv_kernel<<<dim3(512), dim3(512), 0, stream>>>(x, wt, qf, kf, vf);
    attn_kernel<<<dim3(512), dim3(512), 0, stream>>>(qf, kf, vf, out);
}

// Round 14
// 38.926 us; speedup vs baseline: 1.6413x; 1.3830x over previous
//
#include <hip/hip_runtime.h>
#include <hip/hip_bf16.h>

#define B_ 8
#define T_ 2048
#define C_ 1024
#define HS_ 64

typedef float f32x4 __attribute__((ext_vector_type(4)));
typedef __bf16 bf16x8 __attribute__((ext_vector_type(8)));
typedef __bf16 bf16x4 __attribute__((ext_vector_type(4)));

__device__ __forceinline__ void gld_lds16(const void* g, void* l) {
    __builtin_amdgcn_global_load_lds(
        (const __attribute__((address_space(1))) void*)g,
        (__attribute__((address_space(3))) void*)l, 16, 0, 0);
}

// Workspaces:
//  wt[192][1024] bf16, PRE-SWIZZLED per 64-col k-tile: chunk c (16B) of row
//  rw holds original chunk c^(rw&7) (rule #21: source perm == read perm).
//  Rows 0-63 Wq^T (scaled 1/32), 64-127 Wk^T, 128-191 Wv^T.
//  Qf[b*128+qt16][2 half][64 lane][8] : word = Q[qt*16+(lane&15)][half*32+(lane>>4)*8+j]
//  Kf identical mapping. Vf[b*64+kt32][4 ntv][64][8]:
//  word = V[kt32*32+(lane>>4)*8+j][ntv*16+(lane&15)]

// ---------------------------------------------------------------------------
// Kernel 1: W [1024][64] fp32 -> wt [192][1024] bf16, transposed, q scaled,
// chunk-swizzled. VECTORIZED STORES: each thread gathers one (row, chunk)
// 16B word from the LDS tile column and stores it with dwordx4.
// Output word (n, chunk c, elem e) = tile[(c^(n&7))*8 + e][n] * scale.
// ---------------------------------------------------------------------------
__global__ __launch_bounds__(256) void wt_kernel(const float* __restrict__ Wq,
                                                 const float* __restrict__ Wk,
                                                 const float* __restrict__ Wv,
                                                 __bf16* __restrict__ wt) {
    __shared__ float tile[64][65];
    int mb = blockIdx.x >> 4;
    int k0 = (blockIdx.x & 15) * 64;
    const float* W = (mb == 0) ? Wq : (mb == 1 ? Wk : Wv);
    int c = threadIdx.x & 63;
#pragma unroll
    for (int r = threadIdx.x >> 6; r < 64; r += 4)
        tile[r][c] = W[(size_t)(k0 + r) * 64 + c];
    __syncthreads();
    float scale = (mb == 0) ? 0.03125f : 1.0f;
#pragma unroll
    for (int i = 0; i < 2; ++i) {
        int u = threadIdx.x + i * 256;   // 0..511 = 64 rows x 8 chunks
        int n  = u >> 3;
        int ch = u & 7;
        int src = (ch ^ (n & 7)) * 8;
        bf16x8 v;
#pragma unroll
        for (int e = 0; e < 8; ++e)
            v[e] = (__bf16)(tile[src + e][n] * scale);
        *(bf16x8*)(wt + (size_t)(mb * 64 + n) * C_ + k0 + ch * 8) = v;
    }
}

// ---------------------------------------------------------------------------
// Kernel 2: QKV GEMM (r9-exact). 512 blocks x 512 thr. 32 rows x 192 cols,
// K-step 64, W via global_load_lds from pre-swizzled wt, x reg-staged.
// ---------------------------------------------------------------------------
__global__ __launch_bounds__(512) void qkv_kernel(const float* __restrict__ x,
                                                  const __bf16* __restrict__ wt,
                                                  __bf16* __restrict__ qf,
                                                  __bf16* __restrict__ kf,
                                                  __bf16* __restrict__ vf) {
    __shared__ __align__(16) char smem[57344];
    __bf16* xs0 = (__bf16*)smem;               // [32][64] swz, 4KB
    __bf16* xs1 = (__bf16*)(smem + 4096);
    __bf16* ws0 = (__bf16*)(smem + 8192);      // [192][64] swz, 24KB
    __bf16* ws1 = (__bf16*)(smem + 32768);

    const int tid = threadIdx.x;
    const int w = tid >> 6, lane = tid & 63, lq = lane & 15, lg = lane >> 4;
    const int m0 = blockIdx.x * 32;
    const int mt = w & 1;
    const int ntb = (w >> 1) * 3;

    f32x4 acc[3];
#pragma unroll
    for (int i = 0; i < 3; ++i) acc[i] = (f32x4)0.0f;

    const int xrow = tid >> 3, xch = tid & 7;
    float4 xr0, xr1;
    const int wslot0 = w * 3 * 64 + lane;

    if (tid < 256) {
        const float* xp = x + (size_t)(m0 + xrow) * C_ + xch * 8;
        xr0 = *(const float4*)xp;
        xr1 = *(const float4*)(xp + 4);
    }
#pragma unroll
    for (int s = 0; s < 3; ++s) {
        int slot = wslot0 + s * 64;
        gld_lds16(wt + (size_t)(slot >> 3) * C_ + (slot & 7) * 8,
                  ws0 + (w * 3 + s) * 512);
    }
    if (tid < 256) {
        bf16x8 xb;
#pragma unroll
        for (int j = 0; j < 4; ++j) { xb[j] = (__bf16)xr0[j]; xb[4 + j] = (__bf16)xr1[j]; }
        *(bf16x8*)(xs0 + xrow * 64 + ((xch ^ (xrow & 7)) * 8)) = xb;
    }

    for (int kt = 0; kt < 16; ++kt) {
        __syncthreads();
        __bf16* xsc = (kt & 1) ? xs1 : xs0;
        __bf16* wsc = (kt & 1) ? ws1 : ws0;
        __bf16* xsn = (kt & 1) ? xs0 : xs1;
        __bf16* wsn = (kt & 1) ? ws0 : ws1;
        if (kt < 15) {
            int k0 = (kt + 1) * 64;
            if (tid < 256) {
                const float* xp = x + (size_t)(m0 + xrow) * C_ + k0 + xch * 8;
                xr0 = *(const float4*)xp;
                xr1 = *(const float4*)(xp + 4);
            }
#pragma unroll
            for (int s = 0; s < 3; ++s) {
                int slot = wslot0 + s * 64;
                gld_lds16(wt + (size_t)(slot >> 3) * C_ + k0 + (slot & 7) * 8,
                          wsn + (w * 3 + s) * 512);
            }
        }
#pragma unroll
        for (int ks = 0; ks < 2; ++ks) {
            int r = mt * 16 + lq;
            bf16x8 a = *(const bf16x8*)(xsc + r * 64 + (((ks * 4 + lg) ^ (r & 7)) * 8));
#pragma unroll
            for (int i = 0; i < 3; ++i) {
                int rw = (ntb + i) * 16 + lq;
                bf16x8 b = *(const bf16x8*)(wsc + rw * 64 + (((ks * 4 + lg) ^ (rw & 7)) * 8));
                acc[i] = __builtin_amdgcn_mfma_f32_16x16x32_bf16(a, b, acc[i], 0, 0, 0);
            }
        }
        if (kt < 15 && tid < 256) {
            bf16x8 xb;
#pragma unroll
            for (int j = 0; j < 4; ++j) { xb[j] = (__bf16)xr0[j]; xb[4 + j] = (__bf16)xr1[j]; }
            *(bf16x8*)(xsn + xrow * 64 + ((xch ^ (xrow & 7)) * 8)) = xb;
        }
    }
    __syncthreads();

    __bf16(*obuf)[208] = (__bf16(*)[208])smem;
#pragma unroll
    for (int i = 0; i < 3; ++i)
#pragma unroll
        for (int r = 0; r < 4; ++r)
            obuf[mt * 16 + lg * 4 + r][(ntb + i) * 16 + lq] = (__bf16)acc[i][r];
    __syncthreads();

    if (w < 4) {
        int mg = w & 1, half = w >> 1;
        size_t qt16 = (size_t)(m0 >> 4) + mg;
        bf16x8 vq = *(const bf16x8*)&obuf[mg * 16 + lq][half * 32 + lg * 8];
        bf16x8 vk = *(const bf16x8*)&obuf[mg * 16 + lq][64 + half * 32 + lg * 8];
        *(bf16x8*)(qf + ((qt16 * 2 + half) * 64 + lane) * 8) = vq;
        *(bf16x8*)(kf + ((qt16 * 2 + half) * 64 + lane) * 8) = vk;
    } else {
        int ntv = w - 4;
        bf16x8 vv;
#pragma unroll
        for (int j = 0; j < 8; ++j)
            vv[j] = obuf[lg * 8 + j][128 + ntv * 16 + lq];
        size_t kt32 = (size_t)(m0 >> 5);
        *(bf16x8*)(vf + ((kt32 * 4 + ntv) * 64 + lane) * 8) = vv;
    }
}

// ---------------------------------------------------------------------------
// Kernel 3: causal flash attention (r9-exact). 512 blocks x 8 waves; wave-
// paired Q32; swapped QK^T; KVBLK=64; defer-max; V-prefetch; flash-combine.
// ---------------------------------------------------------------------------
__global__ __launch_bounds__(512, 4) void attn_kernel(const __bf16* __restrict__ qf,
                                                      const __bf16* __restrict__ kf,
                                                      const __bf16* __restrict__ vf,
                                                      float* __restrict__ out) {
    __shared__ float olds[8][16][64];
    __shared__ float mlds[8][16], llds[8][16];
    __shared__ __align__(16) __bf16 plds[8][16 * 72];

    int w    = threadIdx.x >> 6;
    int lane = threadIdx.x & 63;
    int lq = lane & 15, lg = lane >> 4;

    int b  = blockIdx.x & 7;
    int q0 = (63 - (blockIdx.x >> 3)) * 32;
    int qs = w >> 2;
    int wk = w & 3;
    int qt = q0 + qs * 16;

    size_t qbase = ((size_t)b * 128 + (qt >> 4)) * 2;
    bf16x8 aq0 = *(const bf16x8*)(qf + ((qbase + 0) * 64 + lane) * 8);
    bf16x8 aq1 = *(const bf16x8*)(qf + ((qbase + 1) * 64 + lane) * 8);

    f32x4 o[4];
#pragma unroll
    for (int nt = 0; nt < 4; ++nt) o[nt] = (f32x4)0.0f;
    float m_s = -1e30f, l_s = 0.f;

    __bf16* pw = &plds[w][0];

    int ntiles = (qt + 79) >> 6;
    for (int kt = wk; kt < ntiles; kt += 4) {
        int s0 = kt * 64;
        f32x4 s[4];
        __builtin_amdgcn_s_setprio(1);
#pragma unroll
        for (int ct = 0; ct < 4; ++ct) {
            size_t kbase = ((size_t)b * 128 + (s0 >> 4) + ct) * 2;
            bf16x8 k0 = *(const bf16x8*)(kf + ((kbase + 0) * 64 + lane) * 8);
            bf16x8 k1 = *(const bf16x8*)(kf + ((kbase + 1) * 64 + lane) * 8);
            f32x4 a = (f32x4)0.0f;
            a = __builtin_amdgcn_mfma_f32_16x16x32_bf16(k0, aq0, a, 0, 0, 0);
            a = __builtin_amdgcn_mfma_f32_16x16x32_bf16(k1, aq1, a, 0, 0, 0);
            s[ct] = a;
        }
        __builtin_amdgcn_s_setprio(0);
        if (s0 + 63 > qt) {
#pragma unroll
            for (int ct = 0; ct < 4; ++ct)
#pragma unroll
                for (int r = 0; r < 4; ++r)
                    if (s0 + ct * 16 + lg * 4 + r > qt + lq) s[ct][r] = -1e30f;
        }
        bf16x8 bv[2][4];
#pragma unroll
        for (int ks = 0; ks < 2; ++ks)
#pragma unroll
            for (int nt = 0; nt < 4; ++nt)
                bv[ks][nt] = *(const bf16x8*)(vf +
                    (((size_t)(b * 64 + (s0 >> 5) + ks) * 4 + nt) * 64 + lane) * 8);
        float pm = -1e30f;
#pragma unroll
        for (int ct = 0; ct < 4; ++ct)
#pragma unroll
            for (int r = 0; r < 4; ++r) pm = fmaxf(pm, s[ct][r]);
        pm = fmaxf(pm, __shfl_xor(pm, 16));
        pm = fmaxf(pm, __shfl_xor(pm, 32));
        bool need = __any(pm > m_s);
        float al = 1.0f;
        if (need) {
            float mn = fmaxf(m_s, pm);
            al = __expf(m_s - mn);
            m_s = mn;
        }
        float rs = 0.f;
        f32x4 p[4];
#pragma unroll
        for (int ct = 0; ct < 4; ++ct)
#pragma unroll
            for (int r = 0; r < 4; ++r) {
                p[ct][r] = __expf(s[ct][r] - m_s);
                rs += p[ct][r];
            }
        rs += __shfl_xor(rs, 16);
        rs += __shfl_xor(rs, 32);
        if (need) {
            l_s = l_s * al + rs;
            float alr[4];
#pragma unroll
            for (int r = 0; r < 4; ++r) alr[r] = __shfl(al, lg * 4 + r);
#pragma unroll
            for (int nt = 0; nt < 4; ++nt)
#pragma unroll
                for (int r = 0; r < 4; ++r) o[nt][r] *= alr[r];
        } else {
            l_s += rs;
        }
#pragma unroll
        for (int ct = 0; ct < 4; ++ct) {
            bf16x4 qv;
#pragma unroll
            for (int r = 0; r < 4; ++r) qv[r] = (__bf16)p[ct][r];
            *(bf16x4*)&pw[lq * 72 + ct * 16 + lg * 4] = qv;
        }
        asm volatile("" ::: "memory");
        bf16x8 pa0 = *(const bf16x8*)&pw[lq * 72 + lg * 8];
        bf16x8 pa1 = *(const bf16x8*)&pw[lq * 72 + 32 + lg * 8];
        __builtin_amdgcn_s_setprio(1);
#pragma unroll
        for (int nt = 0; nt < 4; ++nt) {
            o[nt] = __builtin_amdgcn_mfma_f32_16x16x32_bf16(pa0, bv[0][nt], o[nt], 0, 0, 0);
            o[nt] = __builtin_amdgcn_mfma_f32_16x16x32_bf16(pa1, bv[1][nt], o[nt], 0, 0, 0);
        }
        __builtin_amdgcn_s_setprio(0);
    }

    asm volatile("" ::: "memory");
#pragma unroll
    for (int nt = 0; nt < 4; ++nt)
#pragma unroll
        for (int r = 0; r < 4; ++r)
            olds[w][lg * 4 + r][nt * 16 + lq] = o[nt][r];
    if (lg == 0) {
        mlds[w][lq] = m_s;
        llds[w][lq] = l_s;
    }
    __syncthreads();

    int row = threadIdx.x >> 4;
    int c4  = (threadIdx.x & 15) * 4;
    int wb  = (row >> 4) * 4;
    int r16 = row & 15;
    float M = -1e30f;
#pragma unroll
    for (int w2 = 0; w2 < 4; ++w2) M = fmaxf(M, mlds[wb + w2][r16]);
    float L = 0.f;
    f32x4 oa = (f32x4)0.0f;
#pragma unroll
    for (int w2 = 0; w2 < 4; ++w2) {
        float sc = __expf(mlds[wb + w2][r16] - M);
        L += sc * llds[wb + w2][r16];
        const float* op = &olds[wb + w2][r16][c4];
#pragma unroll
        for (int j = 0; j < 4; ++j) oa[j] += sc * op[j];
    }
    float inv = 1.0f / L;
    float4 st;
    st.x = oa[0] * inv; st.y = oa[1] * inv; st.z = oa[2] * inv; st.w = oa[3] * inv;
    *(float4*)(out + ((size_t)b * T_ + q0 + row) * HS_ + c4) = st;
}

extern "C" void kernel_launch(void* const* d_in, const int* in_sizes, int n_in,
                              void* d_out, int out_size, void* d_ws, size_t ws_size,
                              hipStream_t stream) {
    const float* x  = (const float*)d_in[0];
    const float* Wq = (const float*)d_in[1];
    const float* Wk = (const float*)d_in[2];
    const float* Wv = (const float*)d_in[3];
    char* ws = (char*)d_ws;
    __bf16* wt = (__bf16*)ws;                     // 393216 B
    __bf16* qf = (__bf16*)(ws + 393216);          // 2 MB
    __bf16* kf = (__bf16*)(ws + 2490368);         // 2 MB
    __bf16* vf = (__bf16*)(ws + 4587520);         // 2 MB
    float* out = (float*)d_out;

    wt_kernel<<<dim3(48), dim3(256), 0, stream>>>(Wq, Wk, Wv, wt);
    qkv_kernel<<<dim3(512), dim3(512), 0, stream>>>(x, wt, qf, kf, vf);
    attn_kernel<<<dim3(512), dim3(512), 0, stream>>>(qf, kf, vf, out);
}